// Round 9
// baseline (162.842 us; speedup 1.0000x reference)
//
#include <hip/hip_runtime.h>
#include <math.h>

// (N, Cin, Cout, S, H, W) = (4, 256, 256, 512, 64, 64)
#define NB 4
#define CC 256
#define SS 512
#define NL 6
#define SLOT_HW 65536   // 128 KB per weight slot, MFMA-A-fragment-packed

typedef __attribute__((ext_vector_type(8))) short s16x8;
typedef __attribute__((ext_vector_type(4))) float f32x4;
typedef __attribute__((ext_vector_type(2))) float f32x2;
typedef __attribute__((ext_vector_type(4))) unsigned short u16x4;
typedef __attribute__((ext_vector_type(8))) unsigned short u16x8;

__device__ __forceinline__ unsigned short f2bf(float f) {
    unsigned u = __builtin_bit_cast(unsigned, f);
    u += 0x7FFFu + ((u >> 16) & 1u);
    return (unsigned short)(u >> 16);
}
__device__ __forceinline__ float bf2f(unsigned short h) {
    unsigned u = ((unsigned)h) << 16;
    return __builtin_bit_cast(float, u);
}
// gelu_exact(x) ~= x*sigmoid(1.5957691216*(x+0.044715x^3)), |err|<3e-3
__device__ __forceinline__ float gelu_fast(float x) {
    float u = x * (1.0f + 0.044715f * x * x);
    float e = __expf(-1.5957691216f * u);
    return x / (1.0f + e);
}

// Fragment-packed weight layout, per 256x256 GEMM slot (128 KB):
// fragment f = (m>>4)*8 + (k>>5); inside: halfword offset
//   ((k>>3)&3)*128 + (m&15)*8 + (k&7)
// so a wave's A-fragment read is slot + f*512 + lane*8 (16 B/lane contiguous).

// ---------------------------------------------------------------------------
__global__ __launch_bounds__(256) void wmod_kernel(
    const float* __restrict__ y, const float* __restrict__ aw,
    const float* __restrict__ ab, const float* __restrict__ mw,
    unsigned short* __restrict__ wsBF)
{
    int w = threadIdx.x >> 6, lane = threadIdx.x & 63;
    int r = blockIdx.x*4 + w;      // 0 .. 6143
    int l = r >> 10;
    int b = (r >> 8) & 3;
    int o = r & 255;

    const float* awr = aw + (size_t)(l*CC + o)*SS;
    const float* yb  = y + (size_t)b*SS;
    float s = 0.f;
#pragma unroll
    for (int j = 0; j < 8; ++j) { int idx = lane + 64*j; s += awr[idx]*yb[idx]; }
#pragma unroll
    for (int off = 32; off; off >>= 1) s += __shfl_xor(s, off);
    float t = s + ab[l*CC + o] + 1.0f;

    const float* mwr = mw + (size_t)(l*CC + o)*CC;
    float wv[4]; float ss = 0.f;
#pragma unroll
    for (int u = 0; u < 4; ++u) { int j = lane + 64*u; wv[u] = mwr[j]*t; ss += wv[u]*wv[u]; }
#pragma unroll
    for (int off = 32; off; off >>= 1) ss += __shfl_xor(ss, off);
    float d = 1.0f / sqrtf(ss + 1e-8f);

    unsigned short* slot = wsBF + (size_t)(1 + l*NB + b)*SLOT_HW;
#pragma unroll
    for (int u = 0; u < 4; ++u) {
        int k = lane + 64*u;
        int f = (o >> 4)*8 + (k >> 5);
        int hw = f*512 + ((k >> 3) & 3)*128 + (o & 15)*8 + (k & 7);
        slot[hw] = f2bf(wv[u]*d);
    }
}

__global__ __launch_bounds__(256) void cwsplit_kernel(
    const float* __restrict__ cw, unsigned short* __restrict__ wsBF)
{
    int w = threadIdx.x >> 6, lane = threadIdx.x & 63;
    int m = blockIdx.x*4 + w;      // 0..255
#pragma unroll
    for (int u = 0; u < 4; ++u) {
        int k = lane + 64*u;
        int f = (m >> 4)*8 + (k >> 5);
        int hw = f*512 + ((k >> 3) & 3)*128 + (m & 15)*8 + (k & 7);
        wsBF[hw] = f2bf(cw[(size_t)m*CC + k]);
    }
}

// ---------------------------------------------------------------------------
// Fused: one block = (batch, full 64-px strip, all 256 channels). 256 blocks.
// LDS = EXACTLY 64 KB -> 2 blocks/CU (the round-8 kernel was 2 KB over).
// B-fragment layout, kq OUTERMOST: frag(kq,nt,kcl,hl) of 1 KB. Conv reuses
// slice kq=0 only; xS overlays the idle [16384,33792) of the B region.
#define BFRAG(kq, nt, kcl, hl) \
    (lds + (((((kq)*4 + (nt))*2 + (kcl))*2 + (hl)))*1024)

__global__ __launch_bounds__(512, 4) void fused_kernel(
    const float* __restrict__ x, const float* __restrict__ cb,
    const unsigned short* __restrict__ wsBF, float* __restrict__ out)
{
    // LDS 65536 B: B frags [0,64K). Conv: B slice0 [0,16K) + xS f32[64][68]
    // @16384 (17408 B, ends 33792). Conv epilogue overlays S2 f32[128][66]
    // @0 (33792 B). Layers use the full 64 KB; xS/S2 dead by then.
    __shared__ __align__(16) unsigned char lds[65536];
    float* xS = (float*)(lds + 16384);
    float* S2 = (float*)lds;

    const int tid  = threadIdx.x;
    const int lane = tid & 63;
    const int wid  = tid >> 6;     // 0..7
    const int wm   = wid >> 1;     // 0..3  m base 64*wm; owns k-quarter wm
    const int wn   = wid & 1;      // 0..1  n base 32*wn
    const int l15  = lane & 15;
    const int q    = lane >> 4;    // 0..3

    // XCD swizzle: blockIdx%8 -> batch pair-slot; weights L2-resident per XCD
    const int bswz  = blockIdx.x & 7;
    const int b     = bswz >> 1;                             // 0..3
    const int strip = ((blockIdx.x >> 3) << 1) | (bswz & 1); // 0..63
    const int n0    = strip * 64;

    float y1[4][2][4], y2[4][2][4];
    f32x4 acc[4][2];

    // ---------------- conv GEMM:  acc = cw @ x[b]  ----------------
#pragma unroll
    for (int t = 0; t < 4; ++t)
#pragma unroll
        for (int s = 0; s < 2; ++s) acc[t][s] = 0;

    for (int kq = 0; kq < 4; ++kq) {
        {   // coalesced fp32 stage of x window [64k x 64n]
            int r0 = tid >> 4, c4 = (tid & 15) * 4;
#pragma unroll
            for (int p = 0; p < 2; ++p) {
                int row = r0 + 32*p;
                float4 v = *(const float4*)&x[((size_t)(b*CC + kq*64 + row))*4096 + n0 + c4];
                *(float4*)&xS[row*68 + c4] = v;
            }
        }
        __syncthreads();   // also guards: prev quarter's B-slice0 reads done
        {   // transpose (conflict-free read) -> split bf16 -> B slice 0
            int n = tid & 63, k0 = (tid >> 6) * 8;
            float f[8];
#pragma unroll
            for (int i = 0; i < 8; ++i) f[i] = xS[(k0+i)*68 + n];
            u16x8 hv, lv;
#pragma unroll
            for (int i = 0; i < 8; ++i) {
                unsigned short h = f2bf(f[i]);
                hv[i] = h; lv[i] = f2bf(f[i] - bf2f(h));
            }
            int nt = n >> 4, n15 = n & 15, kcl = k0 >> 5, qq = (k0 >> 3) & 3;
            *(u16x8*)(BFRAG(0,nt,kcl,0) + (16*qq + n15)*16) = hv;
            *(u16x8*)(BFRAG(0,nt,kcl,1) + (16*qq + n15)*16) = lv;
        }
        // A fragment loads global->reg, issued pre-barrier (drain = prefetch)
        s16x8 afr[2][4];
#pragma unroll
        for (int kcl = 0; kcl < 2; ++kcl)
#pragma unroll
        for (int t = 0; t < 4; ++t)
            afr[kcl][t] = *(const s16x8*)(wsBF + (size_t)((4*wm+t)*8 + kq*2+kcl)*512 + lane*8);
        __syncthreads();
#pragma unroll
        for (int kcl = 0; kcl < 2; ++kcl)
#pragma unroll
        for (int s = 0; s < 2; ++s) {
            int nt = 2*wn + s;
            s16x8 bh = *(const s16x8*)(BFRAG(0,nt,kcl,0) + lane*16);
            s16x8 bl = *(const s16x8*)(BFRAG(0,nt,kcl,1) + lane*16);
#pragma unroll
            for (int t = 0; t < 4; ++t) {
                acc[t][s] = __builtin_amdgcn_mfma_f32_16x16x32_bf16(afr[kcl][t], bh, acc[t][s], 0, 0, 0);
                acc[t][s] = __builtin_amdgcn_mfma_f32_16x16x32_bf16(afr[kcl][t], bl, acc[t][s], 0, 0, 0);
            }
        }
    }

    // conv epilogue: bias + channel-duplication remap via fp32 LDS scratch.
    // x1[c] = conv[c>>1]+cb, x2[c] = conv[128+(c>>1)]+cb
#pragma unroll
    for (int pass = 0; pass < 2; ++pass) {
        __syncthreads();
        if ((wm >> 1) == pass) {
#pragma unroll
            for (int t = 0; t < 4; ++t)
#pragma unroll
            for (int s = 0; s < 2; ++s)
#pragma unroll
            for (int r = 0; r < 4; ++r) {
                int m  = 64*wm + 16*t + 4*q + r;
                int nl = 32*wn + 16*s + l15;
                S2[(m - 128*pass)*66 + nl] = acc[t][s][r] + cb[m];
            }
        }
        __syncthreads();
#pragma unroll
        for (int t = 0; t < 4; ++t)
#pragma unroll
        for (int s = 0; s < 2; ++s)
#pragma unroll
        for (int r = 0; r < 4; ++r) {
            int c  = 64*wm + 16*t + 4*q + r;
            int nl = 32*wn + 16*s + l15;
            float v = S2[(c >> 1)*66 + nl];
            if (pass == 0) { y1[t][s][r] = v; }
            else           { y2[t][s][r] = v; y1[t][s][r] += v; }
        }
    }
    __syncthreads();   // S2 reads done before layer-0 staging reuses B region
    // y1 = x1+x2, y2 = x2

    // ---------------- 6 layers: 2 barriers per layer ----------------
    for (int l = 0; l < NL; ++l) {
        const unsigned short* slot = wsBF + (size_t)(1 + l*NB + b)*SLOT_HW;
#pragma unroll
        for (int t = 0; t < 4; ++t)
#pragma unroll
            for (int s = 0; s < 2; ++s) acc[t][s] = 0;

        // stage FULL B from y1 regs: wave (wm,wn) owns k-quarter wm, n-half wn
#pragma unroll
        for (int t = 0; t < 4; ++t)
#pragma unroll
        for (int s = 0; s < 2; ++s) {
            int nt = 2*wn + s, kcl = t >> 1;
            int qq = 2*(t & 1) + (q >> 1), jb = 4*(q & 1);
            u16x4 hv, lv;
#pragma unroll
            for (int r = 0; r < 4; ++r) {
                unsigned short h = f2bf(y1[t][s][r]);
                hv[r] = h; lv[r] = f2bf(y1[t][s][r] - bf2f(h));
            }
            *(u16x4*)(BFRAG(wm,nt,kcl,0) + (16*qq + l15)*16 + jb*2) = hv;
            *(u16x4*)(BFRAG(wm,nt,kcl,1) + (16*qq + l15)*16 + jb*2) = lv;
        }
        // prologue A prefetch for step 0 (issued before the barrier)
        s16x8 aN[4], aC[4];
#pragma unroll
        for (int t = 0; t < 4; ++t)
            aN[t] = *(const s16x8*)(slot + (size_t)((4*wm+t)*8 + 0)*512 + lane*8);
        __syncthreads();
        // ONE long MFMA phase: 8 steps, A prefetched 1 step ahead
#pragma unroll
        for (int step = 0; step < 8; ++step) {
#pragma unroll
            for (int t = 0; t < 4; ++t) aC[t] = aN[t];
            if (step < 7) {
#pragma unroll
                for (int t = 0; t < 4; ++t)
                    aN[t] = *(const s16x8*)(slot + (size_t)((4*wm+t)*8 + step+1)*512 + lane*8);
            }
            int kq = step >> 1, kcl = step & 1;
#pragma unroll
            for (int s = 0; s < 2; ++s) {
                int nt = 2*wn + s;
                s16x8 bh = *(const s16x8*)(BFRAG(kq,nt,kcl,0) + lane*16);
                s16x8 bl = *(const s16x8*)(BFRAG(kq,nt,kcl,1) + lane*16);
#pragma unroll
                for (int t = 0; t < 4; ++t) {
                    acc[t][s] = __builtin_amdgcn_mfma_f32_16x16x32_bf16(aC[t], bh, acc[t][s], 0, 0, 0);
                    acc[t][s] = __builtin_amdgcn_mfma_f32_16x16x32_bf16(aC[t], bl, acc[t][s], 0, 0, 0);
                }
            }
        }
        // y2 += gelu(h); y1 += y2 (next layer), skip on last
#pragma unroll
        for (int t = 0; t < 4; ++t)
#pragma unroll
        for (int s = 0; s < 2; ++s)
#pragma unroll
        for (int r = 0; r < 4; ++r) {
            y2[t][s][r] += gelu_fast(acc[t][s][r]);
            if (l < NL - 1) y1[t][s][r] += y2[t][s][r];
        }
        __syncthreads();   // all B reads done before next layer's staging
    }

    // ---------------- out = 0.5*(y1+y2), 2x2 upsample (nontemporal) --------
#pragma unroll
    for (int t = 0; t < 4; ++t)
#pragma unroll
    for (int s = 0; s < 2; ++s)
#pragma unroll
    for (int r = 0; r < 4; ++r) {
        int ch = 64*wm + 16*t + 4*q + r;
        int w  = 32*wn + 16*s + l15;          // 0..63 source col
        float v = 0.5f*(y1[t][s][r] + y2[t][s][r]);
        f32x2 vv = {v, v};
        size_t base = (((size_t)(b*CC + ch)*128 + 2*strip))*128 + 2*w;
        __builtin_nontemporal_store(vv, (f32x2*)&out[base]);
        __builtin_nontemporal_store(vv, (f32x2*)&out[base + 128]);
    }
}

extern "C" void kernel_launch(void* const* d_in, const int* in_sizes, int n_in,
                              void* d_out, int out_size, void* d_ws, size_t ws_size,
                              hipStream_t stream) {
    const float* x  = (const float*)d_in[0];
    const float* y  = (const float*)d_in[1];
    const float* cw = (const float*)d_in[2];
    const float* cb = (const float*)d_in[3];
    const float* aw = (const float*)d_in[4];
    const float* ab = (const float*)d_in[5];
    const float* mw = (const float*)d_in[6];
    float* out = (float*)d_out;

    unsigned short* wsBF = (unsigned short*)d_ws;   // 25 slots * 128 KB = 3.2 MB

    wmod_kernel<<<NL*NB*CC/4, 256, 0, stream>>>(y, aw, ab, mw, wsBF);
    cwsplit_kernel<<<64, 256, 0, stream>>>(cw, wsBF);
    fused_kernel<<<256, 512, 0, stream>>>(x, cb, wsBF, out);
}

// Round 10
// 139.484 us; speedup vs baseline: 1.1675x; 1.1675x over previous
//
#include <hip/hip_runtime.h>
#include <math.h>

// (N, Cin, Cout, S, H, W) = (4, 256, 256, 512, 64, 64)
#define NB 4
#define CC 256
#define SS 512
#define NL 6
#define SLOT_HW 65536   // 128 KB per weight slot, MFMA-A-fragment-packed

typedef __attribute__((ext_vector_type(8))) short s16x8;
typedef __attribute__((ext_vector_type(4))) float f32x4;
typedef __attribute__((ext_vector_type(2))) float f32x2;
typedef __attribute__((ext_vector_type(4))) unsigned short u16x4;

__device__ __forceinline__ unsigned short f2bf(float f) {
    unsigned u = __builtin_bit_cast(unsigned, f);
    u += 0x7FFFu + ((u >> 16) & 1u);
    return (unsigned short)(u >> 16);
}
__device__ __forceinline__ float bf2f(unsigned short h) {
    unsigned u = ((unsigned)h) << 16;
    return __builtin_bit_cast(float, u);
}
// gelu_exact(x) ~= x*sigmoid(1.5957691216*(x+0.044715x^3)), |err|<3e-3
__device__ __forceinline__ float gelu_fast(float x) {
    float u = x * (1.0f + 0.044715f * x * x);
    float e = __expf(-1.5957691216f * u);
    return x / (1.0f + e);
}

// Fragment-packed weight layout, per 256x256 GEMM slot (128 KB):
// fragment f = (m>>4)*8 + (k>>5); inside: halfword offset
//   ((k>>3)&3)*128 + (m&15)*8 + (k&7)
// so a wave's A-fragment read is slot + f*512 + lane*8 (16 B/lane contiguous).

// ---------------------------------------------------------------------------
__global__ __launch_bounds__(256) void wmod_kernel(
    const float* __restrict__ y, const float* __restrict__ aw,
    const float* __restrict__ ab, const float* __restrict__ mw,
    unsigned short* __restrict__ wsBF)
{
    int w = threadIdx.x >> 6, lane = threadIdx.x & 63;
    int r = blockIdx.x*4 + w;      // 0 .. 6143
    int l = r >> 10;
    int b = (r >> 8) & 3;
    int o = r & 255;

    const float* awr = aw + (size_t)(l*CC + o)*SS;
    const float* yb  = y + (size_t)b*SS;
    float s = 0.f;
#pragma unroll
    for (int j = 0; j < 8; ++j) { int idx = lane + 64*j; s += awr[idx]*yb[idx]; }
#pragma unroll
    for (int off = 32; off; off >>= 1) s += __shfl_xor(s, off);
    float t = s + ab[l*CC + o] + 1.0f;

    const float* mwr = mw + (size_t)(l*CC + o)*CC;
    float wv[4]; float ss = 0.f;
#pragma unroll
    for (int u = 0; u < 4; ++u) { int j = lane + 64*u; wv[u] = mwr[j]*t; ss += wv[u]*wv[u]; }
#pragma unroll
    for (int off = 32; off; off >>= 1) ss += __shfl_xor(ss, off);
    float d = 1.0f / sqrtf(ss + 1e-8f);

    unsigned short* slot = wsBF + (size_t)(1 + l*NB + b)*SLOT_HW;
#pragma unroll
    for (int u = 0; u < 4; ++u) {
        int k = lane + 64*u;
        int f = (o >> 4)*8 + (k >> 5);
        int hw = f*512 + ((k >> 3) & 3)*128 + (o & 15)*8 + (k & 7);
        slot[hw] = f2bf(wv[u]*d);
    }
}

__global__ __launch_bounds__(256) void cwsplit_kernel(
    const float* __restrict__ cw, unsigned short* __restrict__ wsBF)
{
    int w = threadIdx.x >> 6, lane = threadIdx.x & 63;
    int m = blockIdx.x*4 + w;      // 0..255
#pragma unroll
    for (int u = 0; u < 4; ++u) {
        int k = lane + 64*u;
        int f = (m >> 4)*8 + (k >> 5);
        int hw = f*512 + ((k >> 3) & 3)*128 + (m & 15)*8 + (k & 7);
        wsBF[hw] = f2bf(cw[(size_t)m*CC + k]);
    }
}

// ---------------------------------------------------------------------------
// Fused: one block = (batch, 32-px half-strip, all 256 channels). Grid 512
// -> 2 blocks/CU (42 KB LDS each). r8's full-B staging + long MFMA phase.
// B-fragment layout, kq outer: frag(kq,nt,kcl,hl) of 1 KB; nt in {0,1}.
#define BFRAG(kq, nt, kcl, hl) \
    (lds + (((((kq)*2 + (nt))*2 + (kcl))*2 + (hl)))*1024)

__global__ __launch_bounds__(512, 2) void fused_kernel(
    const float* __restrict__ x, const float* __restrict__ cb,
    const unsigned short* __restrict__ wsBF, float* __restrict__ out)
{
    // LDS 41984 B: B frags [0,32K). Conv: slice kq=0 only [0,8K) + xS
    // f32[64][36] @32768 (9216 B). Conv epilogue overlays S2 f32[128][33]
    // @0 (16896 B; conv MFMA reads done by then). Layers use full 32 KB B.
    __shared__ __align__(16) unsigned char lds[41984];
    float* xS = (float*)(lds + 32768);
    float* S2 = (float*)lds;

    const int tid  = threadIdx.x;
    const int lane = tid & 63;
    const int wid  = tid >> 6;     // 0..7
    const int wm   = wid >> 1;     // 0..3  m base 64*wm; owns k-quarter wm
    const int wn   = wid & 1;      // 0..1  n base 16*wn
    const int l15  = lane & 15;
    const int q    = lane >> 4;    // 0..3

    // XCD swizzle: blockIdx%8 -> (batch, half) per XCD; weights L2-resident
    const int bswz  = blockIdx.x & 7;
    const int b     = bswz >> 1;               // 0..3
    const int half  = bswz & 1;                // 0..1
    const int strip = blockIdx.x >> 3;         // 0..63
    const int n0    = strip * 64 + half * 32;  // 32-px window

    float y1[4][4], y2[4][4];
    f32x4 acc[4];

    // ---------------- conv GEMM:  acc = cw @ x[b]  ----------------
#pragma unroll
    for (int t = 0; t < 4; ++t) acc[t] = 0;

    for (int kq = 0; kq < 4; ++kq) {
        {   // coalesced fp32 stage of x window [64k x 32n]
            int row = tid >> 3, c4 = (tid & 7) * 4;
            float4 v = *(const float4*)&x[((size_t)(b*CC + kq*64 + row))*4096 + n0 + c4];
            *(float4*)&xS[row*36 + c4] = v;
        }
        __syncthreads();   // also guards: prev quarter's B-slice0 reads done
        {   // transpose (2-way free read) -> split bf16 -> B slice kq=0
            int n = tid & 31, k0 = (tid >> 5) * 4;   // k0 in 0..60
            float f[4];
#pragma unroll
            for (int i = 0; i < 4; ++i) f[i] = xS[(k0+i)*36 + n];
            u16x4 hv, lv;
#pragma unroll
            for (int i = 0; i < 4; ++i) {
                unsigned short h = f2bf(f[i]);
                hv[i] = h; lv[i] = f2bf(f[i] - bf2f(h));
            }
            int nt = n >> 4, n15 = n & 15, kcl = k0 >> 5, qq = (k0 >> 3) & 3, jb = k0 & 7;
            *(u16x4*)(BFRAG(0,nt,kcl,0) + (16*qq + n15)*16 + jb*2) = hv;
            *(u16x4*)(BFRAG(0,nt,kcl,1) + (16*qq + n15)*16 + jb*2) = lv;
        }
        // A fragment loads global->reg, issued pre-barrier (drain = prefetch)
        s16x8 afr[2][4];
#pragma unroll
        for (int kcl = 0; kcl < 2; ++kcl)
#pragma unroll
        for (int t = 0; t < 4; ++t)
            afr[kcl][t] = *(const s16x8*)(wsBF + (size_t)((4*wm+t)*8 + kq*2+kcl)*512 + lane*8);
        __syncthreads();
#pragma unroll
        for (int kcl = 0; kcl < 2; ++kcl) {
            s16x8 bh = *(const s16x8*)(BFRAG(0,wn,kcl,0) + lane*16);
            s16x8 bl = *(const s16x8*)(BFRAG(0,wn,kcl,1) + lane*16);
#pragma unroll
            for (int t = 0; t < 4; ++t) {
                acc[t] = __builtin_amdgcn_mfma_f32_16x16x32_bf16(afr[kcl][t], bh, acc[t], 0, 0, 0);
                acc[t] = __builtin_amdgcn_mfma_f32_16x16x32_bf16(afr[kcl][t], bl, acc[t], 0, 0, 0);
            }
        }
    }

    // conv epilogue: bias + channel-duplication remap via fp32 LDS scratch.
    // x1[c] = conv[c>>1]+cb, x2[c] = conv[128+(c>>1)]+cb
#pragma unroll
    for (int pass = 0; pass < 2; ++pass) {
        __syncthreads();
        if ((wm >> 1) == pass) {
#pragma unroll
            for (int t = 0; t < 4; ++t)
#pragma unroll
            for (int r = 0; r < 4; ++r) {
                int m  = 64*wm + 16*t + 4*q + r;
                int nl = 16*wn + l15;
                S2[(m - 128*pass)*33 + nl] = acc[t][r] + cb[m];
            }
        }
        __syncthreads();
#pragma unroll
        for (int t = 0; t < 4; ++t)
#pragma unroll
        for (int r = 0; r < 4; ++r) {
            int c  = 64*wm + 16*t + 4*q + r;
            int nl = 16*wn + l15;
            float v = S2[(c >> 1)*33 + nl];
            if (pass == 0) { y1[t][r] = v; }
            else           { y2[t][r] = v; y1[t][r] += v; }
        }
    }
    __syncthreads();   // S2 reads done before layer-0 staging reuses B region
    // y1 = x1+x2, y2 = x2

    // ---------------- 6 layers: 2 barriers per layer ----------------
    for (int l = 0; l < NL; ++l) {
        const unsigned short* slot = wsBF + (size_t)(1 + l*NB + b)*SLOT_HW;
#pragma unroll
        for (int t = 0; t < 4; ++t) acc[t] = 0;

        // stage FULL B from y1 regs: wave (wm,wn) owns k-quarter wm, n-half wn
#pragma unroll
        for (int t = 0; t < 4; ++t) {
            int kcl = t >> 1;
            int qq = 2*(t & 1) + (q >> 1), jb = 4*(q & 1);
            u16x4 hv, lv;
#pragma unroll
            for (int r = 0; r < 4; ++r) {
                unsigned short h = f2bf(y1[t][r]);
                hv[r] = h; lv[r] = f2bf(y1[t][r] - bf2f(h));
            }
            *(u16x4*)(BFRAG(wm,wn,kcl,0) + (16*qq + l15)*16 + jb*2) = hv;
            *(u16x4*)(BFRAG(wm,wn,kcl,1) + (16*qq + l15)*16 + jb*2) = lv;
        }
        // prologue A prefetch for step 0 (issued before the barrier)
        s16x8 aN[4], aC[4];
#pragma unroll
        for (int t = 0; t < 4; ++t)
            aN[t] = *(const s16x8*)(slot + (size_t)((4*wm+t)*8 + 0)*512 + lane*8);
        __syncthreads();
        // ONE long MFMA phase: 8 steps, A prefetched 1 step ahead
#pragma unroll
        for (int step = 0; step < 8; ++step) {
#pragma unroll
            for (int t = 0; t < 4; ++t) aC[t] = aN[t];
            if (step < 7) {
#pragma unroll
                for (int t = 0; t < 4; ++t)
                    aN[t] = *(const s16x8*)(slot + (size_t)((4*wm+t)*8 + step+1)*512 + lane*8);
            }
            int kq = step >> 1, kcl = step & 1;
            s16x8 bh = *(const s16x8*)(BFRAG(kq,wn,kcl,0) + lane*16);
            s16x8 bl = *(const s16x8*)(BFRAG(kq,wn,kcl,1) + lane*16);
#pragma unroll
            for (int t = 0; t < 4; ++t) {
                acc[t] = __builtin_amdgcn_mfma_f32_16x16x32_bf16(aC[t], bh, acc[t], 0, 0, 0);
                acc[t] = __builtin_amdgcn_mfma_f32_16x16x32_bf16(aC[t], bl, acc[t], 0, 0, 0);
            }
        }
        // y2 += gelu(h); y1 += y2 (next layer), skip on last
#pragma unroll
        for (int t = 0; t < 4; ++t)
#pragma unroll
        for (int r = 0; r < 4; ++r) {
            y2[t][r] += gelu_fast(acc[t][r]);
            if (l < NL - 1) y1[t][r] += y2[t][r];
        }
        __syncthreads();   // all B reads done before next layer's staging
    }

    // ---------------- out = 0.5*(y1+y2), 2x2 upsample (nontemporal) --------
#pragma unroll
    for (int t = 0; t < 4; ++t)
#pragma unroll
    for (int r = 0; r < 4; ++r) {
        int ch = 64*wm + 16*t + 4*q + r;
        int w  = half*32 + 16*wn + l15;       // 0..63 source col
        float v = 0.5f*(y1[t][r] + y2[t][r]);
        f32x2 vv = {v, v};
        size_t base = (((size_t)(b*CC + ch)*128 + 2*strip))*128 + 2*w;
        __builtin_nontemporal_store(vv, (f32x2*)&out[base]);
        __builtin_nontemporal_store(vv, (f32x2*)&out[base + 128]);
    }
}

extern "C" void kernel_launch(void* const* d_in, const int* in_sizes, int n_in,
                              void* d_out, int out_size, void* d_ws, size_t ws_size,
                              hipStream_t stream) {
    const float* x  = (const float*)d_in[0];
    const float* y  = (const float*)d_in[1];
    const float* cw = (const float*)d_in[2];
    const float* cb = (const float*)d_in[3];
    const float* aw = (const float*)d_in[4];
    const float* ab = (const float*)d_in[5];
    const float* mw = (const float*)d_in[6];
    float* out = (float*)d_out;

    unsigned short* wsBF = (unsigned short*)d_ws;   // 25 slots * 128 KB = 3.2 MB

    wmod_kernel<<<NL*NB*CC/4, 256, 0, stream>>>(y, aw, ab, mw, wsBF);
    cwsplit_kernel<<<64, 256, 0, stream>>>(cw, wsBF);
    fused_kernel<<<512, 512, 0, stream>>>(x, cb, wsBF, out);
}

// Round 11
// 134.787 us; speedup vs baseline: 1.2081x; 1.0348x over previous
//
#include <hip/hip_runtime.h>
#include <math.h>

// (N, Cin, Cout, S, H, W) = (4, 256, 256, 512, 64, 64)
#define NB 4
#define CC 256
#define SS 512
#define NL 6
#define SLOT_HW 65536   // 128 KB per weight slot, MFMA-A-fragment-packed

typedef __attribute__((ext_vector_type(8))) short s16x8;
typedef __attribute__((ext_vector_type(4))) float f32x4;
typedef __attribute__((ext_vector_type(2))) float f32x2;
typedef __attribute__((ext_vector_type(4))) unsigned short u16x4;

__device__ __forceinline__ unsigned short f2bf(float f) {
    unsigned u = __builtin_bit_cast(unsigned, f);
    u += 0x7FFFu + ((u >> 16) & 1u);
    return (unsigned short)(u >> 16);
}
__device__ __forceinline__ float bf2f(unsigned short h) {
    unsigned u = ((unsigned)h) << 16;
    return __builtin_bit_cast(float, u);
}
// gelu_exact(x) ~= x*sigmoid(1.5957691216*(x+0.044715x^3)), |err|<3e-3
__device__ __forceinline__ float gelu_fast(float x) {
    float u = x * (1.0f + 0.044715f * x * x);
    float e = __expf(-1.5957691216f * u);
    return x / (1.0f + e);
}

// Fragment-packed weight layout, per 256x256 GEMM slot (128 KB):
// fragment f = (m>>4)*8 + (k>>5); inside: halfword offset
//   ((k>>3)&3)*128 + (m&15)*8 + (k&7)
// wave A-fragment read = slot + f*512 + lane*8 (16 B/lane contiguous).

// ---------------------------------------------------------------------------
__global__ __launch_bounds__(256) void wmod_kernel(
    const float* __restrict__ y, const float* __restrict__ aw,
    const float* __restrict__ ab, const float* __restrict__ mw,
    unsigned short* __restrict__ wsBF)
{
    int w = threadIdx.x >> 6, lane = threadIdx.x & 63;
    int r = blockIdx.x*4 + w;      // 0 .. 6143
    int l = r >> 10;
    int b = (r >> 8) & 3;
    int o = r & 255;

    const float* awr = aw + (size_t)(l*CC + o)*SS;
    const float* yb  = y + (size_t)b*SS;
    float s = 0.f;
#pragma unroll
    for (int j = 0; j < 8; ++j) { int idx = lane + 64*j; s += awr[idx]*yb[idx]; }
#pragma unroll
    for (int off = 32; off; off >>= 1) s += __shfl_xor(s, off);
    float t = s + ab[l*CC + o] + 1.0f;

    const float* mwr = mw + (size_t)(l*CC + o)*CC;
    float wv[4]; float ss = 0.f;
#pragma unroll
    for (int u = 0; u < 4; ++u) { int j = lane + 64*u; wv[u] = mwr[j]*t; ss += wv[u]*wv[u]; }
#pragma unroll
    for (int off = 32; off; off >>= 1) ss += __shfl_xor(ss, off);
    float d = 1.0f / sqrtf(ss + 1e-8f);

    unsigned short* slot = wsBF + (size_t)(1 + l*NB + b)*SLOT_HW;
#pragma unroll
    for (int u = 0; u < 4; ++u) {
        int k = lane + 64*u;
        int f = (o >> 4)*8 + (k >> 5);
        int hw = f*512 + ((k >> 3) & 3)*128 + (o & 15)*8 + (k & 7);
        slot[hw] = f2bf(wv[u]*d);
    }
}

__global__ __launch_bounds__(256) void cwsplit_kernel(
    const float* __restrict__ cw, unsigned short* __restrict__ wsBF)
{
    int w = threadIdx.x >> 6, lane = threadIdx.x & 63;
    int m = blockIdx.x*4 + w;      // 0..255
#pragma unroll
    for (int u = 0; u < 4; ++u) {
        int k = lane + 64*u;
        int f = (m >> 4)*8 + (k >> 5);
        int hw = f*512 + ((k >> 3) & 3)*128 + (m & 15)*8 + (k & 7);
        wsBF[hw] = f2bf(cw[(size_t)m*CC + k]);
    }
}

// ---------------------------------------------------------------------------
// Fused: one block = (batch, 32-px half-strip, all 256 channels). Grid 512,
// 64 KB LDS -> 2 blocks/CU. NEW wave mapping: wave w owns m=[32w,32w+32),
// ALL n=32 -> zero A-fragment duplication (A L2 traffic halved vs r10).
// Layer B (hi+lo, 32 KB) double-buffered across layers -> 1 barrier/layer.
#define BFRAGL(buf, kq, nt, kcl, hl) \
    (lds + (buf)*32768 + ((((((kq)*2 + (nt))*2 + (kcl))*2 + (hl))))*1024)
#define BFRAGC(nt, kcl, hl) \
    (lds + 32768 + (((((nt)*2 + (kcl))*2 + (hl))))*1024)

__global__ __launch_bounds__(512, 2) void fused_kernel(
    const float* __restrict__ x, const float* __restrict__ cb,
    const unsigned short* __restrict__ wsBF, float* __restrict__ out)
{
    // LDS 65536 B: layer-B dbuf [0,64K) (32 KB per buf). Conv (before layer 0,
    // all dead after): convB 8 KB @32768, xS f32[64][36] @40960 (9216 B,
    // ends 50176), epilogue S2 f32[128][33] @0 (16896 B).
    __shared__ __align__(16) unsigned char lds[65536];
    float* xS = (float*)(lds + 40960);
    float* S2 = (float*)lds;

    const int tid  = threadIdx.x;
    const int lane = tid & 63;
    const int w    = tid >> 6;     // wave 0..7: owns m-rows [32w, 32w+32)
    const int l15  = lane & 15;
    const int q    = lane >> 4;    // 0..3

    // XCD swizzle: blockIdx%8 -> (batch, half) per XCD; weights L2-resident
    const int bswz  = blockIdx.x & 7;
    const int b     = bswz >> 1;               // 0..3
    const int half  = bswz & 1;                // 0..1
    const int strip = blockIdx.x >> 3;         // 0..63
    const int n0    = strip * 64 + half * 32;  // 32-px window

    // per-thread state: m-tile t in {0,1} (rows 32w+16t), n-tile s in {0,1}
    float y1[2][2][4], y2[2][2][4];
    f32x4 acc[2][2];

    // ---------------- conv GEMM:  acc = cw @ x[b]  ----------------
#pragma unroll
    for (int t = 0; t < 2; ++t)
#pragma unroll
        for (int s = 0; s < 2; ++s) acc[t][s] = 0;

    for (int kq = 0; kq < 4; ++kq) {
        {   // coalesced fp32 stage of x window [64k x 32n]
            int row = tid >> 3, c4 = (tid & 7) * 4;
            float4 v = *(const float4*)&x[((size_t)(b*CC + kq*64 + row))*4096 + n0 + c4];
            *(float4*)&xS[row*36 + c4] = v;
        }
        __syncthreads();   // xS ready; prev quarter's convB reads done
        {   // transpose (2-way free read) -> split bf16 -> convB slice
            int n = tid & 31, k0 = (tid >> 5) * 4;   // k0 in {0,4,...,60}
            float f[4];
#pragma unroll
            for (int i = 0; i < 4; ++i) f[i] = xS[(k0+i)*36 + n];
            u16x4 hv, lv;
#pragma unroll
            for (int i = 0; i < 4; ++i) {
                unsigned short h = f2bf(f[i]);
                hv[i] = h; lv[i] = f2bf(f[i] - bf2f(h));
            }
            int nt = n >> 4, n15 = n & 15;
            int kcl = k0 >> 5, qq = (k0 >> 3) & 3, jb = k0 & 7;
            *(u16x4*)(BFRAGC(nt,kcl,0) + (16*qq + n15)*16 + jb*2) = hv;
            *(u16x4*)(BFRAGC(nt,kcl,1) + (16*qq + n15)*16 + jb*2) = lv;
        }
        // A fragment loads global->reg, issued pre-barrier (drain = prefetch)
        s16x8 afr[2][2];
#pragma unroll
        for (int kcl = 0; kcl < 2; ++kcl)
#pragma unroll
        for (int t = 0; t < 2; ++t)
            afr[kcl][t] = *(const s16x8*)(wsBF + (size_t)(((2*w+t)*8 + kq*2+kcl)*512) + lane*8);
        __syncthreads();
#pragma unroll
        for (int kcl = 0; kcl < 2; ++kcl)
#pragma unroll
        for (int s = 0; s < 2; ++s) {
            s16x8 bh = *(const s16x8*)(BFRAGC(s,kcl,0) + lane*16);
            s16x8 bl = *(const s16x8*)(BFRAGC(s,kcl,1) + lane*16);
#pragma unroll
            for (int t = 0; t < 2; ++t) {
                acc[t][s] = __builtin_amdgcn_mfma_f32_16x16x32_bf16(afr[kcl][t], bh, acc[t][s], 0, 0, 0);
                acc[t][s] = __builtin_amdgcn_mfma_f32_16x16x32_bf16(afr[kcl][t], bl, acc[t][s], 0, 0, 0);
            }
        }
    }

    // conv epilogue: bias + channel-duplication remap via fp32 LDS scratch.
    // x1[c] = conv[c>>1]+cb, x2[c] = conv[128+(c>>1)]+cb
#pragma unroll
    for (int pass = 0; pass < 2; ++pass) {
        __syncthreads();
        if ((w >> 2) == pass) {            // waves owning m in [128pass, +128)
#pragma unroll
            for (int t = 0; t < 2; ++t)
#pragma unroll
            for (int s = 0; s < 2; ++s)
#pragma unroll
            for (int r = 0; r < 4; ++r) {
                int m  = 32*w + 16*t + 4*q + r;
                int nl = 16*s + l15;
                S2[(m - 128*pass)*33 + nl] = acc[t][s][r] + cb[m];
            }
        }
        __syncthreads();
#pragma unroll
        for (int t = 0; t < 2; ++t)
#pragma unroll
        for (int s = 0; s < 2; ++s)
#pragma unroll
        for (int r = 0; r < 4; ++r) {
            int c  = 32*w + 16*t + 4*q + r;
            int nl = 16*s + l15;
            float v = S2[(c >> 1)*33 + nl];
            if (pass == 0) { y1[t][s][r] = v; }
            else           { y2[t][s][r] = v; y1[t][s][r] += v; }
        }
    }
    __syncthreads();   // S2 reads done before layer-0 staging reuses buf0
    // y1 = x1+x2, y2 = x2

    // ---------------- 6 layers: ONE barrier per layer (B dbuf) ----------------
    for (int l = 0; l < NL; ++l) {
        const int buf = l & 1;
        const unsigned short* slot = wsBF + (size_t)(1 + l*NB + b)*SLOT_HW;
#pragma unroll
        for (int t = 0; t < 2; ++t)
#pragma unroll
            for (int s = 0; s < 2; ++s) acc[t][s] = 0;

        // stage B from y1 regs: wave w's rows = k-slice [32w,32w+32), all n
        {
            int kq = w >> 1, kcl = w & 1, jb = 4*(q & 1);
#pragma unroll
            for (int t = 0; t < 2; ++t) {
                int qq = 2*t + (q >> 1);
#pragma unroll
                for (int s = 0; s < 2; ++s) {
                    u16x4 hv, lv;
#pragma unroll
                    for (int r = 0; r < 4; ++r) {
                        unsigned short h = f2bf(y1[t][s][r]);
                        hv[r] = h; lv[r] = f2bf(y1[t][s][r] - bf2f(h));
                    }
                    *(u16x4*)(BFRAGL(buf,kq,s,kcl,0) + (16*qq + l15)*16 + jb*2) = hv;
                    *(u16x4*)(BFRAGL(buf,kq,s,kcl,1) + (16*qq + l15)*16 + jb*2) = lv;
                }
            }
        }
        // prologue A prefetch for step 0 (issued before the barrier)
        s16x8 aN[2], aC[2];
#pragma unroll
        for (int t = 0; t < 2; ++t)
            aN[t] = *(const s16x8*)(slot + (size_t)(((2*w+t)*8 + 0)*512) + lane*8);
        __syncthreads();
        // ONE long MFMA phase: 8 steps, A prefetched 1 step ahead
#pragma unroll
        for (int step = 0; step < 8; ++step) {
#pragma unroll
            for (int t = 0; t < 2; ++t) aC[t] = aN[t];
            if (step < 7) {
#pragma unroll
                for (int t = 0; t < 2; ++t)
                    aN[t] = *(const s16x8*)(slot + (size_t)(((2*w+t)*8 + step+1)*512) + lane*8);
            }
            int kq = step >> 1, kcl = step & 1;
#pragma unroll
            for (int s = 0; s < 2; ++s) {
                s16x8 bh = *(const s16x8*)(BFRAGL(buf,kq,s,kcl,0) + lane*16);
                s16x8 bl = *(const s16x8*)(BFRAGL(buf,kq,s,kcl,1) + lane*16);
#pragma unroll
                for (int t = 0; t < 2; ++t) {
                    acc[t][s] = __builtin_amdgcn_mfma_f32_16x16x32_bf16(aC[t], bh, acc[t][s], 0, 0, 0);
                    acc[t][s] = __builtin_amdgcn_mfma_f32_16x16x32_bf16(aC[t], bl, acc[t][s], 0, 0, 0);
                }
            }
        }
        // y2 += gelu(h); y1 += y2 (next layer), skip on last.
        // No trailing barrier: next layer stages the OTHER buffer; reuse of
        // this buffer sits behind the next layer's barrier.
#pragma unroll
        for (int t = 0; t < 2; ++t)
#pragma unroll
        for (int s = 0; s < 2; ++s)
#pragma unroll
        for (int r = 0; r < 4; ++r) {
            y2[t][s][r] += gelu_fast(acc[t][s][r]);
            if (l < NL - 1) y1[t][s][r] += y2[t][s][r];
        }
    }

    // ---------------- out = 0.5*(y1+y2), 2x2 upsample (nontemporal) --------
#pragma unroll
    for (int t = 0; t < 2; ++t)
#pragma unroll
    for (int s = 0; s < 2; ++s)
#pragma unroll
    for (int r = 0; r < 4; ++r) {
        int ch  = 32*w + 16*t + 4*q + r;
        int wpx = half*32 + 16*s + l15;       // 0..63 source col
        float v = 0.5f*(y1[t][s][r] + y2[t][s][r]);
        f32x2 vv = {v, v};
        size_t base = (((size_t)(b*CC + ch)*128 + 2*strip))*128 + 2*wpx;
        __builtin_nontemporal_store(vv, (f32x2*)&out[base]);
        __builtin_nontemporal_store(vv, (f32x2*)&out[base + 128]);
    }
}

extern "C" void kernel_launch(void* const* d_in, const int* in_sizes, int n_in,
                              void* d_out, int out_size, void* d_ws, size_t ws_size,
                              hipStream_t stream) {
    const float* x  = (const float*)d_in[0];
    const float* y  = (const float*)d_in[1];
    const float* cw = (const float*)d_in[2];
    const float* cb = (const float*)d_in[3];
    const float* aw = (const float*)d_in[4];
    const float* ab = (const float*)d_in[5];
    const float* mw = (const float*)d_in[6];
    float* out = (float*)d_out;

    unsigned short* wsBF = (unsigned short*)d_ws;   // 25 slots * 128 KB = 3.2 MB

    wmod_kernel<<<NL*NB*CC/4, 256, 0, stream>>>(y, aw, ab, mw, wsBF);
    cwsplit_kernel<<<64, 256, 0, stream>>>(cw, wsBF);
    fused_kernel<<<512, 512, 0, stream>>>(x, cb, wsBF, out);
}

// Round 12
// 133.982 us; speedup vs baseline: 1.2154x; 1.0060x over previous
//
#include <hip/hip_runtime.h>
#include <math.h>

// (N, Cin, Cout, S, H, W) = (4, 256, 256, 512, 64, 64)
#define NB 4
#define CC 256
#define SS 512
#define NL 6
#define SLOT_HW 65536   // 128 KB per weight slot, MFMA-A-fragment-packed

typedef __attribute__((ext_vector_type(8))) short s16x8;
typedef __attribute__((ext_vector_type(4))) float f32x4;
typedef __attribute__((ext_vector_type(2))) float f32x2;
typedef __attribute__((ext_vector_type(4))) unsigned short u16x4;

__device__ __forceinline__ unsigned short f2bf(float f) {
    unsigned u = __builtin_bit_cast(unsigned, f);
    u += 0x7FFFu + ((u >> 16) & 1u);
    return (unsigned short)(u >> 16);
}
__device__ __forceinline__ float bf2f(unsigned short h) {
    unsigned u = ((unsigned)h) << 16;
    return __builtin_bit_cast(float, u);
}
// gelu_exact(x) ~= x*sigmoid(1.5957691216*(x+0.044715x^3)), |err|<3e-3
__device__ __forceinline__ float gelu_fast(float x) {
    float u = x * (1.0f + 0.044715f * x * x);
    float e = __expf(-1.5957691216f * u);
    return x / (1.0f + e);
}

// Fragment-packed weight layout, per 256x256 GEMM slot (128 KB):
// fragment f = (m>>4)*8 + (k>>5); inside: halfword offset
//   ((k>>3)&3)*128 + (m&15)*8 + (k&7)
// wave A-fragment read = slot + f*512 + lane*8 (16 B/lane contiguous).

// ---------------------------------------------------------------------------
__global__ __launch_bounds__(256) void wmod_kernel(
    const float* __restrict__ y, const float* __restrict__ aw,
    const float* __restrict__ ab, const float* __restrict__ mw,
    unsigned short* __restrict__ wsBF)
{
    int w = threadIdx.x >> 6, lane = threadIdx.x & 63;
    int r = blockIdx.x*4 + w;      // 0 .. 6143
    int l = r >> 10;
    int b = (r >> 8) & 3;
    int o = r & 255;

    const float* awr = aw + (size_t)(l*CC + o)*SS;
    const float* yb  = y + (size_t)b*SS;
    float s = 0.f;
#pragma unroll
    for (int j = 0; j < 8; ++j) { int idx = lane + 64*j; s += awr[idx]*yb[idx]; }
#pragma unroll
    for (int off = 32; off; off >>= 1) s += __shfl_xor(s, off);
    float t = s + ab[l*CC + o] + 1.0f;

    const float* mwr = mw + (size_t)(l*CC + o)*CC;
    float wv[4]; float ss = 0.f;
#pragma unroll
    for (int u = 0; u < 4; ++u) { int j = lane + 64*u; wv[u] = mwr[j]*t; ss += wv[u]*wv[u]; }
#pragma unroll
    for (int off = 32; off; off >>= 1) ss += __shfl_xor(ss, off);
    float d = 1.0f / sqrtf(ss + 1e-8f);

    unsigned short* slot = wsBF + (size_t)(1 + l*NB + b)*SLOT_HW;
#pragma unroll
    for (int u = 0; u < 4; ++u) {
        int k = lane + 64*u;
        int f = (o >> 4)*8 + (k >> 5);
        int hw = f*512 + ((k >> 3) & 3)*128 + (o & 15)*8 + (k & 7);
        slot[hw] = f2bf(wv[u]*d);
    }
}

__global__ __launch_bounds__(256) void cwsplit_kernel(
    const float* __restrict__ cw, unsigned short* __restrict__ wsBF)
{
    int w = threadIdx.x >> 6, lane = threadIdx.x & 63;
    int m = blockIdx.x*4 + w;      // 0..255
#pragma unroll
    for (int u = 0; u < 4; ++u) {
        int k = lane + 64*u;
        int f = (m >> 4)*8 + (k >> 5);
        int hw = f*512 + ((k >> 3) & 3)*128 + (m & 15)*8 + (k & 7);
        wsBF[hw] = f2bf(cw[(size_t)m*CC + k]);
    }
}

// ---------------------------------------------------------------------------
// Fused: one block = (batch, 32-px half-strip, all 256 channels). Grid 512,
// 64 KB LDS -> 2 blocks/CU. Wave w owns m=[32w,32w+32), all n=32 (zero A
// duplication). Layer B (hi+lo, 32 KB) double-buffered -> 1 barrier/layer.
// NEW r12: A-fragment L2 prefetch pipelined 3 steps deep (L2 latency ~200cyc
// vs ~45cyc/step; depth-1 exposed ~150cyc stall every step).
#define BFRAGL(buf, kq, nt, kcl, hl) \
    (lds + (buf)*32768 + ((((((kq)*2 + (nt))*2 + (kcl))*2 + (hl))))*1024)
#define BFRAGC(nt, kcl, hl) \
    (lds + 32768 + (((((nt)*2 + (kcl))*2 + (hl))))*1024)

__global__ __launch_bounds__(512, 4) void fused_kernel(
    const float* __restrict__ x, const float* __restrict__ cb,
    const unsigned short* __restrict__ wsBF, float* __restrict__ out)
{
    // LDS 65536 B: layer-B dbuf [0,64K). Conv (dead after layer 0 starts):
    // convB 8 KB @32768, xS f32[64][36] @40960 (9216 B), S2 f32[128][33] @0.
    __shared__ __align__(16) unsigned char lds[65536];
    float* xS = (float*)(lds + 40960);
    float* S2 = (float*)lds;

    const int tid  = threadIdx.x;
    const int lane = tid & 63;
    const int w    = tid >> 6;     // wave 0..7: owns m-rows [32w, 32w+32)
    const int l15  = lane & 15;
    const int q    = lane >> 4;    // 0..3

    // XCD swizzle: blockIdx%8 -> (batch, half) per XCD; weights L2-resident
    const int bswz  = blockIdx.x & 7;
    const int b     = bswz >> 1;               // 0..3
    const int half  = bswz & 1;                // 0..1
    const int strip = blockIdx.x >> 3;         // 0..63
    const int n0    = strip * 64 + half * 32;  // 32-px window

    float y1[2][2][4], y2[2][2][4];
    f32x4 acc[2][2];

    // ---------------- conv GEMM:  acc = cw @ x[b]  ----------------
#pragma unroll
    for (int t = 0; t < 2; ++t)
#pragma unroll
        for (int s = 0; s < 2; ++s) acc[t][s] = 0;

    for (int kq = 0; kq < 4; ++kq) {
        {   // coalesced fp32 stage of x window [64k x 32n]
            int row = tid >> 3, c4 = (tid & 7) * 4;
            float4 v = *(const float4*)&x[((size_t)(b*CC + kq*64 + row))*4096 + n0 + c4];
            *(float4*)&xS[row*36 + c4] = v;
        }
        __syncthreads();   // xS ready; prev quarter's convB reads done
        {   // transpose (2-way free read) -> split bf16 -> convB slice
            int n = tid & 31, k0 = (tid >> 5) * 4;   // k0 in {0,4,...,60}
            float f[4];
#pragma unroll
            for (int i = 0; i < 4; ++i) f[i] = xS[(k0+i)*36 + n];
            u16x4 hv, lv;
#pragma unroll
            for (int i = 0; i < 4; ++i) {
                unsigned short h = f2bf(f[i]);
                hv[i] = h; lv[i] = f2bf(f[i] - bf2f(h));
            }
            int nt = n >> 4, n15 = n & 15;
            int kcl = k0 >> 5, qq = (k0 >> 3) & 3, jb = k0 & 7;
            *(u16x4*)(BFRAGC(nt,kcl,0) + (16*qq + n15)*16 + jb*2) = hv;
            *(u16x4*)(BFRAGC(nt,kcl,1) + (16*qq + n15)*16 + jb*2) = lv;
        }
        // A fragment loads global->reg, issued pre-barrier (drain = prefetch)
        s16x8 afr[2][2];
#pragma unroll
        for (int kcl = 0; kcl < 2; ++kcl)
#pragma unroll
        for (int t = 0; t < 2; ++t)
            afr[kcl][t] = *(const s16x8*)(wsBF + (size_t)(((2*w+t)*8 + kq*2+kcl)*512) + lane*8);
        __syncthreads();
#pragma unroll
        for (int kcl = 0; kcl < 2; ++kcl)
#pragma unroll
        for (int s = 0; s < 2; ++s) {
            s16x8 bh = *(const s16x8*)(BFRAGC(s,kcl,0) + lane*16);
            s16x8 bl = *(const s16x8*)(BFRAGC(s,kcl,1) + lane*16);
#pragma unroll
            for (int t = 0; t < 2; ++t) {
                acc[t][s] = __builtin_amdgcn_mfma_f32_16x16x32_bf16(afr[kcl][t], bh, acc[t][s], 0, 0, 0);
                acc[t][s] = __builtin_amdgcn_mfma_f32_16x16x32_bf16(afr[kcl][t], bl, acc[t][s], 0, 0, 0);
            }
        }
    }

    // conv epilogue: bias + channel-duplication remap via fp32 LDS scratch.
    // x1[c] = conv[c>>1]+cb, x2[c] = conv[128+(c>>1)]+cb
#pragma unroll
    for (int pass = 0; pass < 2; ++pass) {
        __syncthreads();
        if ((w >> 2) == pass) {            // waves owning m in [128pass, +128)
#pragma unroll
            for (int t = 0; t < 2; ++t)
#pragma unroll
            for (int s = 0; s < 2; ++s)
#pragma unroll
            for (int r = 0; r < 4; ++r) {
                int m  = 32*w + 16*t + 4*q + r;
                int nl = 16*s + l15;
                S2[(m - 128*pass)*33 + nl] = acc[t][s][r] + cb[m];
            }
        }
        __syncthreads();
#pragma unroll
        for (int t = 0; t < 2; ++t)
#pragma unroll
        for (int s = 0; s < 2; ++s)
#pragma unroll
        for (int r = 0; r < 4; ++r) {
            int c  = 32*w + 16*t + 4*q + r;
            int nl = 16*s + l15;
            float v = S2[(c >> 1)*33 + nl];
            if (pass == 0) { y1[t][s][r] = v; }
            else           { y2[t][s][r] = v; y1[t][s][r] += v; }
        }
    }
    __syncthreads();   // S2 reads done before layer-0 staging reuses buf0
    // y1 = x1+x2, y2 = x2

    // ---------------- 6 layers: ONE barrier per layer (B dbuf) ----------------
    for (int l = 0; l < NL; ++l) {
        const int buf = l & 1;
        const unsigned short* slot = wsBF + (size_t)(1 + l*NB + b)*SLOT_HW;
#pragma unroll
        for (int t = 0; t < 2; ++t)
#pragma unroll
            for (int s = 0; s < 2; ++s) acc[t][s] = 0;

        // stage B from y1 regs: wave w's rows = k-slice [32w,32w+32), all n
        {
            int kq = w >> 1, kcl = w & 1, jb = 4*(q & 1);
#pragma unroll
            for (int t = 0; t < 2; ++t) {
                int qq = 2*t + (q >> 1);
#pragma unroll
                for (int s = 0; s < 2; ++s) {
                    u16x4 hv, lv;
#pragma unroll
                    for (int r = 0; r < 4; ++r) {
                        unsigned short h = f2bf(y1[t][s][r]);
                        hv[r] = h; lv[r] = f2bf(y1[t][s][r] - bf2f(h));
                    }
                    *(u16x4*)(BFRAGL(buf,kq,s,kcl,0) + (16*qq + l15)*16 + jb*2) = hv;
                    *(u16x4*)(BFRAGL(buf,kq,s,kcl,1) + (16*qq + l15)*16 + jb*2) = lv;
                }
            }
        }
        // A prefetch pipeline, depth 3: issue steps 0..2 before the barrier
        s16x8 aS[8][2];
#pragma unroll
        for (int p = 0; p < 3; ++p)
#pragma unroll
        for (int t = 0; t < 2; ++t)
            aS[p][t] = *(const s16x8*)(slot + (size_t)(((2*w+t)*8 + p)*512) + lane*8);
        __syncthreads();
        // ONE long MFMA phase: 8 steps, A prefetched 3 steps ahead
#pragma unroll
        for (int step = 0; step < 8; ++step) {
            if (step < 5) {
#pragma unroll
                for (int t = 0; t < 2; ++t)
                    aS[step+3][t] = *(const s16x8*)(slot + (size_t)(((2*w+t)*8 + step+3)*512) + lane*8);
            }
            int kq = step >> 1, kcl = step & 1;
#pragma unroll
            for (int s = 0; s < 2; ++s) {
                s16x8 bh = *(const s16x8*)(BFRAGL(buf,kq,s,kcl,0) + lane*16);
                s16x8 bl = *(const s16x8*)(BFRAGL(buf,kq,s,kcl,1) + lane*16);
#pragma unroll
                for (int t = 0; t < 2; ++t) {
                    acc[t][s] = __builtin_amdgcn_mfma_f32_16x16x32_bf16(aS[step][t], bh, acc[t][s], 0, 0, 0);
                    acc[t][s] = __builtin_amdgcn_mfma_f32_16x16x32_bf16(aS[step][t], bl, acc[t][s], 0, 0, 0);
                }
            }
        }
        // y2 += gelu(h); y1 += y2 (next layer), skip on last.
        // No trailing barrier: next layer stages the OTHER buffer.
#pragma unroll
        for (int t = 0; t < 2; ++t)
#pragma unroll
        for (int s = 0; s < 2; ++s)
#pragma unroll
        for (int r = 0; r < 4; ++r) {
            y2[t][s][r] += gelu_fast(acc[t][s][r]);
            if (l < NL - 1) y1[t][s][r] += y2[t][s][r];
        }
    }

    // ---------------- out = 0.5*(y1+y2), 2x2 upsample (nontemporal) --------
#pragma unroll
    for (int t = 0; t < 2; ++t)
#pragma unroll
    for (int s = 0; s < 2; ++s)
#pragma unroll
    for (int r = 0; r < 4; ++r) {
        int ch  = 32*w + 16*t + 4*q + r;
        int wpx = half*32 + 16*s + l15;       // 0..63 source col
        float v = 0.5f*(y1[t][s][r] + y2[t][s][r]);
        f32x2 vv = {v, v};
        size_t base = (((size_t)(b*CC + ch)*128 + 2*strip))*128 + 2*wpx;
        __builtin_nontemporal_store(vv, (f32x2*)&out[base]);
        __builtin_nontemporal_store(vv, (f32x2*)&out[base + 128]);
    }
}

extern "C" void kernel_launch(void* const* d_in, const int* in_sizes, int n_in,
                              void* d_out, int out_size, void* d_ws, size_t ws_size,
                              hipStream_t stream) {
    const float* x  = (const float*)d_in[0];
    const float* y  = (const float*)d_in[1];
    const float* cw = (const float*)d_in[2];
    const float* cb = (const float*)d_in[3];
    const float* aw = (const float*)d_in[4];
    const float* ab = (const float*)d_in[5];
    const float* mw = (const float*)d_in[6];
    float* out = (float*)d_out;

    unsigned short* wsBF = (unsigned short*)d_ws;   // 25 slots * 128 KB = 3.2 MB

    wmod_kernel<<<NL*NB*CC/4, 256, 0, stream>>>(y, aw, ab, mw, wsBF);
    cwsplit_kernel<<<64, 256, 0, stream>>>(cw, wsBF);
    fused_kernel<<<512, 512, 0, stream>>>(x, cb, wsBF, out);
}

// Round 13
// 122.163 us; speedup vs baseline: 1.3330x; 1.0967x over previous
//
#include <hip/hip_runtime.h>
#include <math.h>

// (N, Cin, Cout, S, H, W) = (4, 256, 256, 512, 64, 64)
#define NB 4
#define CC 256
#define SS 512
#define NL 6
#define SLOT_HW 65536   // 128 KB per weight slot, MFMA-A-fragment-packed

typedef __attribute__((ext_vector_type(8))) short s16x8;
typedef __attribute__((ext_vector_type(4))) float f32x4;
typedef __attribute__((ext_vector_type(2))) float f32x2;
typedef __attribute__((ext_vector_type(4))) unsigned short u16x4;

__device__ __forceinline__ unsigned short f2bf(float f) {
    unsigned u = __builtin_bit_cast(unsigned, f);
    u += 0x7FFFu + ((u >> 16) & 1u);
    return (unsigned short)(u >> 16);
}
// gelu_exact(x) ~= x*sigmoid(1.5957691216*(x+0.044715x^3)), |err|<3e-3;
// division via v_rcp_f32 (approx, ~1ulp).
__device__ __forceinline__ float gelu_fast(float x) {
    float u = x * (1.0f + 0.044715f * x * x);
    float e = __expf(-1.5957691216f * u);
    return x * __builtin_amdgcn_rcpf(1.0f + e);
}

// Fragment-packed weight layout, per 256x256 GEMM slot (128 KB):
// fragment f = (m>>4)*8 + (k>>5); inside: halfword offset
//   ((k>>3)&3)*128 + (m&15)*8 + (k&7)
// wave A-fragment read = slot + f*512 + lane*8 (16 B/lane contiguous).

// ---------------------------------------------------------------------------
__global__ __launch_bounds__(256) void wmod_kernel(
    const float* __restrict__ y, const float* __restrict__ aw,
    const float* __restrict__ ab, const float* __restrict__ mw,
    unsigned short* __restrict__ wsBF)
{
    int w = threadIdx.x >> 6, lane = threadIdx.x & 63;
    int r = blockIdx.x*4 + w;      // 0 .. 6143
    int l = r >> 10;
    int b = (r >> 8) & 3;
    int o = r & 255;

    const float* awr = aw + (size_t)(l*CC + o)*SS;
    const float* yb  = y + (size_t)b*SS;
    float s = 0.f;
#pragma unroll
    for (int j = 0; j < 8; ++j) { int idx = lane + 64*j; s += awr[idx]*yb[idx]; }
#pragma unroll
    for (int off = 32; off; off >>= 1) s += __shfl_xor(s, off);
    float t = s + ab[l*CC + o] + 1.0f;

    const float* mwr = mw + (size_t)(l*CC + o)*CC;
    float wv[4]; float ss = 0.f;
#pragma unroll
    for (int u = 0; u < 4; ++u) { int j = lane + 64*u; wv[u] = mwr[j]*t; ss += wv[u]*wv[u]; }
#pragma unroll
    for (int off = 32; off; off >>= 1) ss += __shfl_xor(ss, off);
    float d = 1.0f / sqrtf(ss + 1e-8f);

    unsigned short* slot = wsBF + (size_t)(1 + l*NB + b)*SLOT_HW;
#pragma unroll
    for (int u = 0; u < 4; ++u) {
        int k = lane + 64*u;
        int f = (o >> 4)*8 + (k >> 5);
        int hw = f*512 + ((k >> 3) & 3)*128 + (o & 15)*8 + (k & 7);
        slot[hw] = f2bf(wv[u]*d);
    }
}

__global__ __launch_bounds__(256) void cwsplit_kernel(
    const float* __restrict__ cw, unsigned short* __restrict__ wsBF)
{
    int w = threadIdx.x >> 6, lane = threadIdx.x & 63;
    int m = blockIdx.x*4 + w;      // 0..255
#pragma unroll
    for (int u = 0; u < 4; ++u) {
        int k = lane + 64*u;
        int f = (m >> 4)*8 + (k >> 5);
        int hw = f*512 + ((k >> 3) & 3)*128 + (m & 15)*8 + (k & 7);
        wsBF[hw] = f2bf(cw[(size_t)m*CC + k]);
    }
}

// ---------------------------------------------------------------------------
// Fused: one block = (batch, 32-px half-strip, all 256 channels). Grid 512,
// 45 KB LDS -> 2 blocks/CU. Wave w owns m=[32w,32w+32), all n=32 (zero A
// duplication). r13: B is plain bf16 (no hi+lo) -> halves MFMA count, halves
// B LDS traffic, halves split VALU. State y1/y2 stays fp32 in registers.
// Layer B (16 KB) double-buffered -> 1 barrier/layer; A prefetch depth 3.
#define BFRAGL(buf, kq, nt, kcl) \
    (lds + (buf)*16384 + ((((kq)*2 + (nt))*2 + (kcl)))*1024)
#define BFRAGC(nt, kcl) \
    (lds + 32768 + (((nt)*2 + (kcl)))*1024)

__global__ __launch_bounds__(512, 4) void fused_kernel(
    const float* __restrict__ x, const float* __restrict__ cb,
    const unsigned short* __restrict__ wsBF, float* __restrict__ out)
{
    // LDS 46080 B: layer-B dbuf [0,32K). Conv (dead after layer 0 starts):
    // convB 4 KB @32768, xS f32[64][36] @36864 (9216 B, ends 46080),
    // epilogue S2 f32[128][33] @0 (16896 B).
    __shared__ __align__(16) unsigned char lds[46080];
    float* xS = (float*)(lds + 36864);
    float* S2 = (float*)lds;

    const int tid  = threadIdx.x;
    const int lane = tid & 63;
    const int w    = tid >> 6;     // wave 0..7: owns m-rows [32w, 32w+32)
    const int l15  = lane & 15;
    const int q    = lane >> 4;    // 0..3

    // XCD swizzle: blockIdx%8 -> (batch, half) per XCD; weights L2-resident
    const int bswz  = blockIdx.x & 7;
    const int b     = bswz >> 1;               // 0..3
    const int half  = bswz & 1;                // 0..1
    const int strip = blockIdx.x >> 3;         // 0..63
    const int n0    = strip * 64 + half * 32;  // 32-px window

    float y1[2][2][4], y2[2][2][4];
    f32x4 acc[2][2];

    // ---------------- conv GEMM:  acc = cw @ x[b]  ----------------
#pragma unroll
    for (int t = 0; t < 2; ++t)
#pragma unroll
        for (int s = 0; s < 2; ++s) acc[t][s] = 0;

    for (int kq = 0; kq < 4; ++kq) {
        {   // coalesced fp32 stage of x window [64k x 32n]
            int row = tid >> 3, c4 = (tid & 7) * 4;
            float4 v = *(const float4*)&x[((size_t)(b*CC + kq*64 + row))*4096 + n0 + c4];
            *(float4*)&xS[row*36 + c4] = v;
        }
        __syncthreads();   // xS ready; prev quarter's convB reads done
        {   // transpose (2-way free read) -> bf16 -> convB slice
            int n = tid & 31, k0 = (tid >> 5) * 4;   // k0 in {0,4,...,60}
            u16x4 hv;
#pragma unroll
            for (int i = 0; i < 4; ++i) hv[i] = f2bf(xS[(k0+i)*36 + n]);
            int nt = n >> 4, n15 = n & 15;
            int kcl = k0 >> 5, qq = (k0 >> 3) & 3, jb = k0 & 7;
            *(u16x4*)(BFRAGC(nt,kcl) + (16*qq + n15)*16 + jb*2) = hv;
        }
        // A fragment loads global->reg, issued pre-barrier (drain = prefetch)
        s16x8 afr[2][2];
#pragma unroll
        for (int kcl = 0; kcl < 2; ++kcl)
#pragma unroll
        for (int t = 0; t < 2; ++t)
            afr[kcl][t] = *(const s16x8*)(wsBF + (size_t)(((2*w+t)*8 + kq*2+kcl)*512) + lane*8);
        __syncthreads();
#pragma unroll
        for (int kcl = 0; kcl < 2; ++kcl)
#pragma unroll
        for (int s = 0; s < 2; ++s) {
            s16x8 bh = *(const s16x8*)(BFRAGC(s,kcl) + lane*16);
#pragma unroll
            for (int t = 0; t < 2; ++t)
                acc[t][s] = __builtin_amdgcn_mfma_f32_16x16x32_bf16(afr[kcl][t], bh, acc[t][s], 0, 0, 0);
        }
    }

    // conv epilogue: bias + channel-duplication remap via fp32 LDS scratch.
    // x1[c] = conv[c>>1]+cb, x2[c] = conv[128+(c>>1)]+cb
#pragma unroll
    for (int pass = 0; pass < 2; ++pass) {
        __syncthreads();
        if ((w >> 2) == pass) {            // waves owning m in [128pass, +128)
#pragma unroll
            for (int t = 0; t < 2; ++t)
#pragma unroll
            for (int s = 0; s < 2; ++s)
#pragma unroll
            for (int r = 0; r < 4; ++r) {
                int m  = 32*w + 16*t + 4*q + r;
                int nl = 16*s + l15;
                S2[(m - 128*pass)*33 + nl] = acc[t][s][r] + cb[m];
            }
        }
        __syncthreads();
#pragma unroll
        for (int t = 0; t < 2; ++t)
#pragma unroll
        for (int s = 0; s < 2; ++s)
#pragma unroll
        for (int r = 0; r < 4; ++r) {
            int c  = 32*w + 16*t + 4*q + r;
            int nl = 16*s + l15;
            float v = S2[(c >> 1)*33 + nl];
            if (pass == 0) { y1[t][s][r] = v; }
            else           { y2[t][s][r] = v; y1[t][s][r] += v; }
        }
    }
    __syncthreads();   // S2 reads done before layer-0 staging reuses buf0
    // y1 = x1+x2, y2 = x2

    // ---------------- 6 layers: ONE barrier per layer (B dbuf) ----------------
    for (int l = 0; l < NL; ++l) {
        const int buf = l & 1;
        const unsigned short* slot = wsBF + (size_t)(1 + l*NB + b)*SLOT_HW;
#pragma unroll
        for (int t = 0; t < 2; ++t)
#pragma unroll
            for (int s = 0; s < 2; ++s) acc[t][s] = 0;

        // stage B (bf16) from y1 regs: wave w's rows = k-slice [32w,32w+32)
        {
            int kq = w >> 1, kcl = w & 1, jb = 4*(q & 1);
#pragma unroll
            for (int t = 0; t < 2; ++t) {
                int qq = 2*t + (q >> 1);
#pragma unroll
                for (int s = 0; s < 2; ++s) {
                    u16x4 hv;
#pragma unroll
                    for (int r = 0; r < 4; ++r) hv[r] = f2bf(y1[t][s][r]);
                    *(u16x4*)(BFRAGL(buf,kq,s,kcl) + (16*qq + l15)*16 + jb*2) = hv;
                }
            }
        }
        // A prefetch pipeline, depth 3: issue steps 0..2 before the barrier
        s16x8 aS[8][2];
#pragma unroll
        for (int p = 0; p < 3; ++p)
#pragma unroll
        for (int t = 0; t < 2; ++t)
            aS[p][t] = *(const s16x8*)(slot + (size_t)(((2*w+t)*8 + p)*512) + lane*8);
        __syncthreads();
        // ONE long MFMA phase: 8 steps, A prefetched 3 steps ahead
#pragma unroll
        for (int step = 0; step < 8; ++step) {
            if (step < 5) {
#pragma unroll
                for (int t = 0; t < 2; ++t)
                    aS[step+3][t] = *(const s16x8*)(slot + (size_t)(((2*w+t)*8 + step+3)*512) + lane*8);
            }
            int kq = step >> 1, kcl = step & 1;
#pragma unroll
            for (int s = 0; s < 2; ++s) {
                s16x8 bh = *(const s16x8*)(BFRAGL(buf,kq,s,kcl) + lane*16);
#pragma unroll
                for (int t = 0; t < 2; ++t)
                    acc[t][s] = __builtin_amdgcn_mfma_f32_16x16x32_bf16(aS[step][t], bh, acc[t][s], 0, 0, 0);
            }
        }
        // y2 += gelu(h); y1 += y2 (next layer), skip on last.
        // No trailing barrier: next layer stages the OTHER buffer.
#pragma unroll
        for (int t = 0; t < 2; ++t)
#pragma unroll
        for (int s = 0; s < 2; ++s)
#pragma unroll
        for (int r = 0; r < 4; ++r) {
            y2[t][s][r] += gelu_fast(acc[t][s][r]);
            if (l < NL - 1) y1[t][s][r] += y2[t][s][r];
        }
    }

    // ---------------- out = 0.5*(y1+y2), 2x2 upsample (nontemporal) --------
#pragma unroll
    for (int t = 0; t < 2; ++t)
#pragma unroll
    for (int s = 0; s < 2; ++s)
#pragma unroll
    for (int r = 0; r < 4; ++r) {
        int ch  = 32*w + 16*t + 4*q + r;
        int wpx = half*32 + 16*s + l15;       // 0..63 source col
        float v = 0.5f*(y1[t][s][r] + y2[t][s][r]);
        f32x2 vv = {v, v};
        size_t base = (((size_t)(b*CC + ch)*128 + 2*strip))*128 + 2*wpx;
        __builtin_nontemporal_store(vv, (f32x2*)&out[base]);
        __builtin_nontemporal_store(vv, (f32x2*)&out[base + 128]);
    }
}

extern "C" void kernel_launch(void* const* d_in, const int* in_sizes, int n_in,
                              void* d_out, int out_size, void* d_ws, size_t ws_size,
                              hipStream_t stream) {
    const float* x  = (const float*)d_in[0];
    const float* y  = (const float*)d_in[1];
    const float* cw = (const float*)d_in[2];
    const float* cb = (const float*)d_in[3];
    const float* aw = (const float*)d_in[4];
    const float* ab = (const float*)d_in[5];
    const float* mw = (const float*)d_in[6];
    float* out = (float*)d_out;

    unsigned short* wsBF = (unsigned short*)d_ws;   // 25 slots * 128 KB = 3.2 MB

    wmod_kernel<<<NL*NB*CC/4, 256, 0, stream>>>(y, aw, ab, mw, wsBF);
    cwsplit_kernel<<<64, 256, 0, stream>>>(cw, wsBF);
    fused_kernel<<<512, 512, 0, stream>>>(x, cb, wsBF, out);
}